// Round 6
// baseline (132.618 us; speedup 1.0000x reference)
//
#include <hip/hip_runtime.h>
#include <hip/hip_bf16.h>
#include <hip/hip_fp16.h>

// ESN cell update, MI355X. B=512, D=256, N=8192, NNZ=134217.
//
// 3-dispatch pipeline:
//   1. hipMemsetAsync: zero per-column counters (32 KB)
//   2. prep_k: state [B,N] f32 -> stateTh [N,B] fp16 (b-pairs packed in uint),
//      inputs -> inputsT f32, COO scatter into per-column buckets with the
//      value pre-duplicated as half2{v,v}.
//   3. spmm_k: one block (128 thr = 2 waves) per 8 columns, full B=512.
//      Thread t owns b=4t..4t+3 (one uint2 = 2 half2 per gather). Columns are
//      processed sequentially; entry/count/param loads are BLOCK-UNIFORM
//      (blockIdx + loop counters only, all-restrict no-clobber) -> scalar-pipe
//      s_load (worst case 1 vector dwordx4 per 2 nnz). Exact per-column
//      counts (no lockstep padding), zero LDS in the gather loop. Epilogue:
//      win + fast-tanh + leaky integrate -> tbuf reshuffle -> row-major out.
//
// Precision: fp16 state (10-bit mantissa); val dup ~5e-4 rel; fp16 accumulate
// over ~16 terms ~2e-4 abs. Threshold 1.8e-2, observed absmax 3.9e-3.

#define ESN_B 512
#define ESN_D 256
#define ESN_N 8192
#define ESN_ALPHA 0.9f
#define CAP  128   // bucket capacity per column (Poisson(16.4): P(>128)~0)
#define G    8     // columns per spmm block

__device__ __forceinline__ unsigned pack_h2(float lo, float hi) {
    return (unsigned)__half_as_ushort(__float2half(lo)) |
           ((unsigned)__half_as_ushort(__float2half(hi)) << 16);
}

__device__ __forceinline__ __half2 int_as_h2(int u) {
    union { int i; __half2 h; } c; c.i = u; return c.h;
}

__device__ __forceinline__ float fast_tanh(float x) {
    x = fminf(fmaxf(x, -9.0f), 9.0f);
    const float e = __expf(2.0f * x);
    return (e - 1.0f) * __builtin_amdgcn_rcpf(e + 1.0f);
}

__global__ __launch_bounds__(256) void prep_k(const float* __restrict__ state,
                                              const float* __restrict__ inputs,
                                              const int* __restrict__ wres_rows,
                                              const int* __restrict__ wres_cols,
                                              const float* __restrict__ wres_vals,
                                              int* __restrict__ cnt,
                                              int2* __restrict__ bucket,
                                              unsigned* __restrict__ stateTh,
                                              float* __restrict__ inputsT,
                                              int nnz) {
    __shared__ unsigned utile[64][33];   // [n-col][b-pair] packed fp16x2
    __shared__ float    tile2[32][33];
    const int t = blockIdx.x;
    const int tid = threadIdx.x;
    const int NB_TS = (ESN_N / 64) * (ESN_B / 64);  // 1024 state tiles (64x64)
    const int NB_TI = (ESN_D / 32) * (ESN_B / 32);  // 128 input tiles

    if (t < NB_TS) {
        // state [512, 8192] f32 -> stateTh [8192, 256] uint (fp16 b-pairs)
        const int bx = t & 127, by = t >> 7;        // N/64 = 128 tiles in x
        const int c0 = bx * 64, r0 = by * 64;
        const int x = tid & 15, yp = tid >> 4;      // x: float4-col, yp: b-pair
#pragma unroll
        for (int i = 0; i < 2; ++i) {
            const int ypi = yp + 16 * i;            // b-pair 0..31
            const float4 v0 = *(const float4*)(state + (size_t)(r0 + 2 * ypi) * ESN_N + c0 + 4 * x);
            const float4 v1 = *(const float4*)(state + (size_t)(r0 + 2 * ypi + 1) * ESN_N + c0 + 4 * x);
            utile[4 * x + 0][ypi] = pack_h2(v0.x, v1.x);
            utile[4 * x + 1][ypi] = pack_h2(v0.y, v1.y);
            utile[4 * x + 2][ypi] = pack_h2(v0.z, v1.z);
            utile[4 * x + 3][ypi] = pack_h2(v0.w, v1.w);
        }
        __syncthreads();
        const int j = tid & 31, nn0 = tid >> 5;     // j: b-pair, nn0: n-row base
#pragma unroll
        for (int i = 0; i < 8; ++i) {
            const int nn = nn0 + 8 * i;
            stateTh[(size_t)(c0 + nn) * (ESN_B / 2) + (r0 >> 1) + j] = utile[nn][j];
        }
    } else if (t < NB_TS + NB_TI) {
        // inputs [512, 256] -> inputsT [256, 512] f32
        const int t2 = t - NB_TS;
        const int bx = t2 & 7, by = t2 >> 3;
        const int tx = tid & 31, ty = tid >> 5;
        const int c0 = bx * 32, r0 = by * 32;
#pragma unroll
        for (int j = ty; j < 32; j += 8)
            tile2[j][tx] = inputs[(size_t)(r0 + j) * ESN_D + c0 + tx];
        __syncthreads();
#pragma unroll
        for (int j = ty; j < 32; j += 8)
            inputsT[(size_t)(c0 + j) * ESN_B + r0 + tx] = tile2[tx][j];
    } else {
        // COO scatter; val pre-duplicated as half2{v,v}
        const int i = (t - NB_TS - NB_TI) * 256 + tid;
        if (i < nnz) {
            const int c = wres_cols[i];
            const int p = atomicAdd(&cnt[c], 1);
            if (p < CAP) {
                const unsigned short h = __half_as_ushort(__float2half(wres_vals[i]));
                const unsigned hv2 = (unsigned)h | ((unsigned)h << 16);
                bucket[(size_t)c * CAP + p] = make_int2(wres_rows[i], (int)hv2);
            }
        }
    }
}

__global__ __launch_bounds__(128, 4) void spmm_k(const int* __restrict__ cnt,
                                                 const int2* __restrict__ bucket,
                                                 const unsigned* __restrict__ stateTh,
                                                 const float* __restrict__ inputsT,
                                                 const float* __restrict__ win_vals,
                                                 const float* __restrict__ win_bias,
                                                 const int* __restrict__ win_rows,
                                                 float* __restrict__ out) {
    const int c0 = blockIdx.x * G;
    const int t = threadIdx.x;                     // 0..127; owns b = 4t..4t+3
    const uint2* __restrict__ strow = (const uint2*)stateTh;  // row = 128 uint2

    __shared__ float tbuf[G][516];                 // [col][b] reshuffle buffer

#pragma unroll
    for (int g = 0; g < G; ++g) {
        const int c = c0 + g;                      // block-uniform
        int n = cnt[c];                            // -> s_load
        n = (n > CAP) ? CAP : n;
        const int4* __restrict__ ep = (const int4*)(bucket + (size_t)c * CAP);

        __half2 a0 = __half2half2(__ushort_as_half(0));
        __half2 a1 = a0;
        int k = 0;
        for (; k + 2 <= n; k += 2) {
            const int4 e = ep[k >> 1];             // 2 entries, uniform -> s_load
            const uint2 p0 = strow[((unsigned)e.x << 7) + t];
            a0 = __hfma2(int_as_h2(p0.x), int_as_h2(e.y), a0);
            a1 = __hfma2(int_as_h2(p0.y), int_as_h2(e.y), a1);
            const uint2 p1 = strow[((unsigned)e.z << 7) + t];
            a0 = __hfma2(int_as_h2(p1.x), int_as_h2(e.w), a0);
            a1 = __hfma2(int_as_h2(p1.y), int_as_h2(e.w), a1);
        }
        if (k < n) {
            const int2 e = bucket[(size_t)c * CAP + k];
            const uint2 p0 = strow[((unsigned)e.x << 7) + t];
            a0 = __hfma2(int_as_h2(p0.x), int_as_h2(e.y), a0);
            a1 = __hfma2(int_as_h2(p0.y), int_as_h2(e.y), a1);
        }

        // epilogue for column c, this thread's 4 b's
        const float vv = win_vals[c];              // uniform -> s_load
        const float bb = win_bias[c];
        const int   wr = win_rows[c];
        const uint2  ps  = strow[((unsigned)c << 7) + t];       // leak state
        const float4 inp = *(const float4*)(inputsT + (size_t)wr * ESN_B + 4 * t);
        const float s0 = __low2float(int_as_h2(ps.x)), s1 = __high2float(int_as_h2(ps.x));
        const float s2 = __low2float(int_as_h2(ps.y)), s3 = __high2float(int_as_h2(ps.y));
        float4 o;
        o.x = s0 + ESN_ALPHA * (fast_tanh(inp.x * vv + bb + __low2float(a0))  - s0);
        o.y = s1 + ESN_ALPHA * (fast_tanh(inp.y * vv + bb + __high2float(a0)) - s1);
        o.z = s2 + ESN_ALPHA * (fast_tanh(inp.z * vv + bb + __low2float(a1))  - s2);
        o.w = s3 + ESN_ALPHA * (fast_tanh(inp.w * vv + bb + __high2float(a1)) - s3);
        *(float4*)(&tbuf[g][4 * t]) = o;
    }
    __syncthreads();

    // reshuffle -> row-major out (each b-row's 8 cols = 2 float4 stores)
#pragma unroll
    for (int s = t; s < 2 * ESN_B; s += 128) {
        const int jj = s & 1;            // which float4 of the 8 cols
        const int bl = s >> 1;           // b-row 0..511
        const float4 o4 = make_float4(tbuf[4 * jj + 0][bl], tbuf[4 * jj + 1][bl],
                                      tbuf[4 * jj + 2][bl], tbuf[4 * jj + 3][bl]);
        *(float4*)(out + (size_t)bl * ESN_N + c0 + 4 * jj) = o4;
    }
}

extern "C" void kernel_launch(void* const* d_in, const int* in_sizes, int n_in,
                              void* d_out, int out_size, void* d_ws, size_t ws_size,
                              hipStream_t stream) {
    const float* inputs    = (const float*)d_in[0];  // [B, D]
    const float* state     = (const float*)d_in[1];  // [B, N]
    const float* win_vals  = (const float*)d_in[2];  // [N]
    const float* win_bias  = (const float*)d_in[3];  // [N]
    const float* wres_vals = (const float*)d_in[4];  // [NNZ]
    const int*   win_rows  = (const int*)d_in[5];    // [N]
    const int*   wres_rows = (const int*)d_in[6];    // [NNZ]
    const int*   wres_cols = (const int*)d_in[7];    // [NNZ]
    float* out = (float*)d_out;                      // [B, N]

    const int NNZ = in_sizes[4];

    char* w = (char*)d_ws;
    unsigned* stateTh = (unsigned*)(w);                                  // 8 MB
    float*    inputsT = (float*)(w + (size_t)ESN_N * (ESN_B / 2) * 4);   // 512 KB
    int2*     bucket  = (int2*)((char*)inputsT + (size_t)ESN_D * ESN_B * 4); // 8 MB
    int*      cnt     = (int*)((char*)bucket + (size_t)ESN_N * CAP * 8); // 32 KB

    hipMemsetAsync(cnt, 0, ESN_N * sizeof(int), stream);

    const int nb_sc = (NNZ + 255) / 256;
    const int nb = (ESN_N / 64) * (ESN_B / 64) + (ESN_D / 32) * (ESN_B / 32) + nb_sc;
    prep_k<<<nb, 256, 0, stream>>>(state, inputs, wres_rows, wres_cols, wres_vals,
                                   cnt, bucket, stateTh, inputsT, NNZ);

    spmm_k<<<ESN_N / G, 128, 0, stream>>>(cnt, bucket, stateTh, inputsT,
                                          win_vals, win_bias, win_rows, out);
}

// Round 7
// 112.186 us; speedup vs baseline: 1.1821x; 1.1821x over previous
//
#include <hip/hip_runtime.h>
#include <hip/hip_bf16.h>
#include <hip/hip_fp16.h>

// ESN cell update, MI355X. B=512, D=256, N=8192, NNZ=134217.
//
// 3-dispatch pipeline (R5 structure, 4x-amortized entry feed):
//   1. hipMemsetAsync: zero per-column counters (32 KB)
//   2. prep_k: state [B,N] f32 -> stateTh [N,B] fp16 (b-pairs packed in uint),
//      inputs -> inputsT f32, COO scatter into per-column buckets; each entry
//      packed in ONE dword: (row << 16) | fp16(val)  (row < 8192 fits 13b).
//   3. spmm_k: grid = (N/16 col-tiles) x 2 batch-slices of 256 b, 256 thr =
//      4 waves, wave owns 4 cols. Per wave-k ONE ds_read_b128 broadcast feeds
//      all 4 cols (packed entries); each lane covers 4 b (uint2 gather ->
//      2 v_pk_fma_f16 per col). slice = blockIdx&1 -> under round-robin
//      block->XCD each XCD touches a 4 MB fp16 b-slice (L2-resident).
//      Epilogue: win + fast-tanh + leaky integrate -> tbuf reshuffle ->
//      coalesced float4 row-major out.
//
// NOTE (R6 lesson): scalar-pipe uniform entry loads serialize the k-loop
// (spmm 16 -> 47 us). Entry feed must stay LDS-broadcast + wide TLP.
//
// Precision: fp16 state/vals; accumulate over ~16 terms ~1e-3 abs.
// Threshold 1.8e-2, observed absmax 3.9e-3 (output-bf16-rounding dominated).

#define ESN_B 512
#define ESN_D 256
#define ESN_N 8192
#define ESN_ALPHA 0.9f
#define CAP  128   // bucket capacity per column (Poisson(16.4): P(>128)~0)
#define LCAP 64    // LDS-staged capacity (P(nnz/col > 64) ~ 1e-20)
#define G    16    // columns per spmm block
#define NSLICE 2   // batch slices (256 b each, 4 MB fp16 per slice)

__device__ __forceinline__ unsigned pack_h2(float lo, float hi) {
    return (unsigned)__half_as_ushort(__float2half(lo)) |
           ((unsigned)__half_as_ushort(__float2half(hi)) << 16);
}

__device__ __forceinline__ __half2 int_as_h2(unsigned u) {
    union { unsigned i; __half2 h; } c; c.i = u; return c.h;
}

// duplicate the low 16 bits of e into both halves -> half2{val, val}
__device__ __forceinline__ __half2 duplo_h2(unsigned e) {
    return int_as_h2((e << 16) | (e & 0xFFFFu));
}

__device__ __forceinline__ float fast_tanh(float x) {
    x = fminf(fmaxf(x, -9.0f), 9.0f);
    const float e = __expf(2.0f * x);
    return (e - 1.0f) * __builtin_amdgcn_rcpf(e + 1.0f);
}

__global__ __launch_bounds__(256) void prep_k(const float* __restrict__ state,
                                              const float* __restrict__ inputs,
                                              const int* __restrict__ wres_rows,
                                              const int* __restrict__ wres_cols,
                                              const float* __restrict__ wres_vals,
                                              int* __restrict__ cnt,
                                              unsigned* __restrict__ bucket,
                                              unsigned* __restrict__ stateTh,
                                              float* __restrict__ inputsT,
                                              int nnz) {
    __shared__ unsigned utile[64][33];   // [n-col][b-pair] packed fp16x2
    __shared__ float    tile2[32][33];
    const int t = blockIdx.x;
    const int tid = threadIdx.x;
    const int NB_TS = (ESN_N / 64) * (ESN_B / 64);  // 1024 state tiles (64x64)
    const int NB_TI = (ESN_D / 32) * (ESN_B / 32);  // 128 input tiles

    if (t < NB_TS) {
        // state [512, 8192] f32 -> stateTh [8192, 256] uint (fp16 b-pairs)
        const int bx = t & 127, by = t >> 7;        // N/64 = 128 tiles in x
        const int c0 = bx * 64, r0 = by * 64;
        const int x = tid & 15, yp = tid >> 4;      // x: float4-col, yp: b-pair
#pragma unroll
        for (int i = 0; i < 2; ++i) {
            const int ypi = yp + 16 * i;            // b-pair 0..31
            const float4 v0 = *(const float4*)(state + (size_t)(r0 + 2 * ypi) * ESN_N + c0 + 4 * x);
            const float4 v1 = *(const float4*)(state + (size_t)(r0 + 2 * ypi + 1) * ESN_N + c0 + 4 * x);
            utile[4 * x + 0][ypi] = pack_h2(v0.x, v1.x);
            utile[4 * x + 1][ypi] = pack_h2(v0.y, v1.y);
            utile[4 * x + 2][ypi] = pack_h2(v0.z, v1.z);
            utile[4 * x + 3][ypi] = pack_h2(v0.w, v1.w);
        }
        __syncthreads();
        const int j = tid & 31, nn0 = tid >> 5;     // j: b-pair, nn0: n-row base
#pragma unroll
        for (int i = 0; i < 8; ++i) {
            const int nn = nn0 + 8 * i;
            stateTh[(size_t)(c0 + nn) * (ESN_B / 2) + (r0 >> 1) + j] = utile[nn][j];
        }
    } else if (t < NB_TS + NB_TI) {
        // inputs [512, 256] -> inputsT [256, 512] f32
        const int t2 = t - NB_TS;
        const int bx = t2 & 7, by = t2 >> 3;
        const int tx = tid & 31, ty = tid >> 5;
        const int c0 = bx * 32, r0 = by * 32;
#pragma unroll
        for (int j = ty; j < 32; j += 8)
            tile2[j][tx] = inputs[(size_t)(r0 + j) * ESN_D + c0 + tx];
        __syncthreads();
#pragma unroll
        for (int j = ty; j < 32; j += 8)
            inputsT[(size_t)(c0 + j) * ESN_B + r0 + tx] = tile2[tx][j];
    } else {
        // COO scatter; entry packed as (row << 16) | fp16(val)
        const int i = (t - NB_TS - NB_TI) * 256 + tid;
        if (i < nnz) {
            const int c = wres_cols[i];
            const int p = atomicAdd(&cnt[c], 1);
            if (p < CAP) {
                const unsigned h = (unsigned)__half_as_ushort(__float2half(wres_vals[i]));
                bucket[(size_t)c * CAP + p] = ((unsigned)wres_rows[i] << 16) | h;
            }
        }
    }
}

__global__ __launch_bounds__(256, 4) void spmm_k(const int* __restrict__ cnt,
                                                 const unsigned* __restrict__ bucket,
                                                 const unsigned* __restrict__ stateTh,
                                                 const float* __restrict__ inputsT,
                                                 const float* __restrict__ win_vals,
                                                 const float* __restrict__ win_bias,
                                                 const int* __restrict__ win_rows,
                                                 float* __restrict__ out) {
    const int slice = blockIdx.x & (NSLICE - 1);   // -> XCD parity (round-robin)
    const int tile  = blockIdx.x >> 1;
    const int c0 = tile * G;
    const int b0 = slice * 256;                    // this block's 256 b's
    const int lane = threadIdx.x & 63;
    const int w    = threadIdx.x >> 6;             // wave 0..3 owns cols 4w..4w+3
    const int g0 = 4 * w;

    __shared__ unsigned ebuf[LCAP][G + 4];         // packed entries, row 80 B
    __shared__ int   scnt[G];
    __shared__ int   swr[G];
    __shared__ float sval[G], sbias[G];
    __shared__ float tbuf[G][260];                 // [col][b-local] reshuffle

    if (threadIdx.x < G) {
        const int c = c0 + threadIdx.x;
        const int n = cnt[c];
        scnt[threadIdx.x]  = (n > LCAP) ? LCAP : n;
        swr[threadIdx.x]   = win_rows[c];
        sval[threadIdx.x]  = win_vals[c];
        sbias[threadIdx.x] = win_bias[c];
    }
    __syncthreads();

    // stage + zero-pad nnz lists (coalesced global read, transposed LDS write)
#pragma unroll
    for (int s = 0; s < G * LCAP; s += 256) {
        const int idx = s + threadIdx.x;
        const int g = idx >> 6, k = idx & (LCAP - 1);
        ebuf[k][g] = (k < scnt[g]) ? bucket[(size_t)(c0 + g) * CAP + k] : 0u;
    }
    __syncthreads();

    int nmax = scnt[g0];
    nmax = max(nmax, scnt[g0 + 1]);
    nmax = max(nmax, scnt[g0 + 2]);
    nmax = max(nmax, scnt[g0 + 3]);

    // gather: per k ONE ds_read_b128 (broadcast, 4 packed entries = 4 cols);
    // per col: uint2 load (4 fp16 b's) + 2 v_pk_fma_f16.
    const uint2* __restrict__ strow2 = (const uint2*)stateTh;  // row = 128 uint2
    const unsigned boff = (unsigned)(slice * 64) + lane;       // uint2 idx in row
    __half2 a00 = int_as_h2(0u), a01 = a00, a10 = a00, a11 = a00;
    __half2 a20 = a00, a21 = a00, a30 = a00, a31 = a00;
    for (int k = 0; k < nmax; ++k) {
        const uint4 e = *(const uint4*)&ebuf[k][g0];
        const uint2 p0 = strow2[((e.x >> 16) << 7) + boff];
        const uint2 p1 = strow2[((e.y >> 16) << 7) + boff];
        const uint2 p2 = strow2[((e.z >> 16) << 7) + boff];
        const uint2 p3 = strow2[((e.w >> 16) << 7) + boff];
        const __half2 v0 = duplo_h2(e.x), v1 = duplo_h2(e.y);
        const __half2 v2 = duplo_h2(e.z), v3 = duplo_h2(e.w);
        a00 = __hfma2(int_as_h2(p0.x), v0, a00);
        a01 = __hfma2(int_as_h2(p0.y), v0, a01);
        a10 = __hfma2(int_as_h2(p1.x), v1, a10);
        a11 = __hfma2(int_as_h2(p1.y), v1, a11);
        a20 = __hfma2(int_as_h2(p2.x), v2, a20);
        a21 = __hfma2(int_as_h2(p2.y), v2, a21);
        a30 = __hfma2(int_as_h2(p3.x), v3, a30);
        a31 = __hfma2(int_as_h2(p3.y), v3, a31);
    }
    __half2 alo[4] = {a00, a10, a20, a30};   // b = 4*lane+0, 4*lane+1
    __half2 ahi[4] = {a01, a11, a21, a31};   // b = 4*lane+2, 4*lane+3

    // epilogue: win + tanh + leaky integration for 4 cols x 4 b's
#pragma unroll
    for (int g = 0; g < 4; ++g) {
        const int c = g0 + g;
        const uint2 ps = strow2[((unsigned)(c0 + c) << 7) + boff]; // leak state
        const float s0 = __low2float(int_as_h2(ps.x)), s1 = __high2float(int_as_h2(ps.x));
        const float s2 = __low2float(int_as_h2(ps.y)), s3 = __high2float(int_as_h2(ps.y));
        const float4 inp = *(const float4*)(inputsT + (size_t)swr[c] * ESN_B + b0 + 4 * lane);
        const float vv = sval[c], bb = sbias[c];
        float4 o;
        o.x = s0 + ESN_ALPHA * (fast_tanh(inp.x * vv + bb + __low2float(alo[g]))  - s0);
        o.y = s1 + ESN_ALPHA * (fast_tanh(inp.y * vv + bb + __high2float(alo[g])) - s1);
        o.z = s2 + ESN_ALPHA * (fast_tanh(inp.z * vv + bb + __low2float(ahi[g]))  - s2);
        o.w = s3 + ESN_ALPHA * (fast_tanh(inp.w * vv + bb + __high2float(ahi[g])) - s3);
        *(float4*)(&tbuf[c][4 * lane]) = o;   // row stride 1040 B, 16B-aligned
    }
    __syncthreads();

    // reshuffle -> row-major out: 256 b-rows x 16 cols = 1024 float4 stores,
    // lanes 0..3 cover one 64 B run of a row -> coalesced.
#pragma unroll
    for (int s = threadIdx.x; s < 4 * 256; s += 256) {
        const int jj = s & 3;            // which float4 within the 16 cols
        const int bl = s >> 2;           // b-local 0..255
        const float4 o4 = make_float4(tbuf[4 * jj + 0][bl], tbuf[4 * jj + 1][bl],
                                      tbuf[4 * jj + 2][bl], tbuf[4 * jj + 3][bl]);
        *(float4*)(out + (size_t)(b0 + bl) * ESN_N + c0 + 4 * jj) = o4;
    }
}

extern "C" void kernel_launch(void* const* d_in, const int* in_sizes, int n_in,
                              void* d_out, int out_size, void* d_ws, size_t ws_size,
                              hipStream_t stream) {
    const float* inputs    = (const float*)d_in[0];  // [B, D]
    const float* state     = (const float*)d_in[1];  // [B, N]
    const float* win_vals  = (const float*)d_in[2];  // [N]
    const float* win_bias  = (const float*)d_in[3];  // [N]
    const float* wres_vals = (const float*)d_in[4];  // [NNZ]
    const int*   win_rows  = (const int*)d_in[5];    // [N]
    const int*   wres_rows = (const int*)d_in[6];    // [NNZ]
    const int*   wres_cols = (const int*)d_in[7];    // [NNZ]
    float* out = (float*)d_out;                      // [B, N]

    const int NNZ = in_sizes[4];

    char* w = (char*)d_ws;
    unsigned* stateTh = (unsigned*)(w);                                  // 8 MB
    float*    inputsT = (float*)(w + (size_t)ESN_N * (ESN_B / 2) * 4);   // 512 KB
    unsigned* bucket  = (unsigned*)((char*)inputsT + (size_t)ESN_D * ESN_B * 4); // 4 MB
    int*      cnt     = (int*)((char*)bucket + (size_t)ESN_N * CAP * 4); // 32 KB

    hipMemsetAsync(cnt, 0, ESN_N * sizeof(int), stream);

    const int nb_sc = (NNZ + 255) / 256;
    const int nb = (ESN_N / 64) * (ESN_B / 64) + (ESN_D / 32) * (ESN_B / 32) + nb_sc;
    prep_k<<<nb, 256, 0, stream>>>(state, inputs, wres_rows, wres_cols, wres_vals,
                                   cnt, bucket, stateTh, inputsT, NNZ);

    spmm_k<<<(ESN_N / G) * NSLICE, 256, 0, stream>>>(cnt, bucket, stateTh, inputsT,
                                                     win_vals, win_bias, win_rows, out);
}

// Round 8
// 109.134 us; speedup vs baseline: 1.2152x; 1.0280x over previous
//
#include <hip/hip_runtime.h>
#include <hip/hip_bf16.h>
#include <hip/hip_fp16.h>

// ESN cell update, MI355X. B=512, D=256, N=8192, NNZ=134217.
//
// 3-dispatch pipeline:
//   1. hipMemsetAsync: zero per-column counters (32 KB)
//   2. prep_k: state [B,N] f32 -> stateTh [N,B] fp16 (b-pairs packed in uint),
//      inputs -> inputsT f32, COO scatter into per-column buckets; entry
//      packed in ONE dword: (row << 16) | fp16(val).
//   3. spmm_k: grid = (N/16 col-tiles) x 2 batch-slices of 256 b, 256 thr =
//      4 waves. Wave owns 4 columns, processed SEQUENTIALLY with each
//      column's EXACT count (zero-padded only to a multiple of 4; R7's
//      lockstep max over 4 cols wasted ~50% of iterations). Per 4-entry
//      chunk: one ds_read_b128 broadcast + 4 independent uint2 gathers
//      (4 fp16 b's each) + 2 v_pk_fma_f16 per entry. slice = blockIdx&1 ->
//      4 MB fp16 b-slice per XCD (L2-resident). Epilogue: win + fast-tanh +
//      leaky integrate -> tbuf reshuffle -> coalesced float4 row-major out.
//
// R6 lesson: scalar-pipe uniform entry loads serialize the k-loop. Feed must
// stay LDS-broadcast + wide TLP.
//
// Precision: fp16 state/vals; accumulate over ~16 terms ~1e-3 abs.
// Threshold 1.8e-2, observed absmax 3.9e-3.

#define ESN_B 512
#define ESN_D 256
#define ESN_N 8192
#define ESN_ALPHA 0.9f
#define CAP  128   // bucket capacity per column (Poisson(16.4): P(>128)~0)
#define LCAP 64    // LDS-staged capacity (P(nnz/col > 64) ~ 1e-20)
#define G    16    // columns per spmm block
#define NSLICE 2   // batch slices (256 b each, 4 MB fp16 per slice)

__device__ __forceinline__ unsigned pack_h2(float lo, float hi) {
    return (unsigned)__half_as_ushort(__float2half(lo)) |
           ((unsigned)__half_as_ushort(__float2half(hi)) << 16);
}

__device__ __forceinline__ __half2 int_as_h2(unsigned u) {
    union { unsigned i; __half2 h; } c; c.i = u; return c.h;
}

// duplicate the low 16 bits of e into both halves -> half2{val, val}
__device__ __forceinline__ __half2 duplo_h2(unsigned e) {
    return int_as_h2((e << 16) | (e & 0xFFFFu));
}

__device__ __forceinline__ float fast_tanh(float x) {
    x = fminf(fmaxf(x, -9.0f), 9.0f);
    const float e = __expf(2.0f * x);
    return (e - 1.0f) * __builtin_amdgcn_rcpf(e + 1.0f);
}

__global__ __launch_bounds__(256) void prep_k(const float* __restrict__ state,
                                              const float* __restrict__ inputs,
                                              const int* __restrict__ wres_rows,
                                              const int* __restrict__ wres_cols,
                                              const float* __restrict__ wres_vals,
                                              int* __restrict__ cnt,
                                              unsigned* __restrict__ bucket,
                                              unsigned* __restrict__ stateTh,
                                              float* __restrict__ inputsT,
                                              int nnz) {
    __shared__ unsigned utile[64][33];   // [n-col][b-pair] packed fp16x2
    __shared__ float    tile2[32][33];
    const int t = blockIdx.x;
    const int tid = threadIdx.x;
    const int NB_TS = (ESN_N / 64) * (ESN_B / 64);  // 1024 state tiles (64x64)
    const int NB_TI = (ESN_D / 32) * (ESN_B / 32);  // 128 input tiles

    if (t < NB_TS) {
        // state [512, 8192] f32 -> stateTh [8192, 256] uint (fp16 b-pairs)
        const int bx = t & 127, by = t >> 7;        // N/64 = 128 tiles in x
        const int c0 = bx * 64, r0 = by * 64;
        const int x = tid & 15, yp = tid >> 4;      // x: float4-col, yp: b-pair
#pragma unroll
        for (int i = 0; i < 2; ++i) {
            const int ypi = yp + 16 * i;            // b-pair 0..31
            const float4 v0 = *(const float4*)(state + (size_t)(r0 + 2 * ypi) * ESN_N + c0 + 4 * x);
            const float4 v1 = *(const float4*)(state + (size_t)(r0 + 2 * ypi + 1) * ESN_N + c0 + 4 * x);
            utile[4 * x + 0][ypi] = pack_h2(v0.x, v1.x);
            utile[4 * x + 1][ypi] = pack_h2(v0.y, v1.y);
            utile[4 * x + 2][ypi] = pack_h2(v0.z, v1.z);
            utile[4 * x + 3][ypi] = pack_h2(v0.w, v1.w);
        }
        __syncthreads();
        const int j = tid & 31, nn0 = tid >> 5;     // j: b-pair, nn0: n-row base
#pragma unroll
        for (int i = 0; i < 8; ++i) {
            const int nn = nn0 + 8 * i;
            stateTh[(size_t)(c0 + nn) * (ESN_B / 2) + (r0 >> 1) + j] = utile[nn][j];
        }
    } else if (t < NB_TS + NB_TI) {
        // inputs [512, 256] -> inputsT [256, 512] f32
        const int t2 = t - NB_TS;
        const int bx = t2 & 7, by = t2 >> 3;
        const int tx = tid & 31, ty = tid >> 5;
        const int c0 = bx * 32, r0 = by * 32;
#pragma unroll
        for (int j = ty; j < 32; j += 8)
            tile2[j][tx] = inputs[(size_t)(r0 + j) * ESN_D + c0 + tx];
        __syncthreads();
#pragma unroll
        for (int j = ty; j < 32; j += 8)
            inputsT[(size_t)(c0 + j) * ESN_B + r0 + tx] = tile2[tx][j];
    } else {
        // COO scatter; entry packed as (row << 16) | fp16(val)
        const int i = (t - NB_TS - NB_TI) * 256 + tid;
        if (i < nnz) {
            const int c = wres_cols[i];
            const int p = atomicAdd(&cnt[c], 1);
            if (p < CAP) {
                const unsigned h = (unsigned)__half_as_ushort(__float2half(wres_vals[i]));
                bucket[(size_t)c * CAP + p] = ((unsigned)wres_rows[i] << 16) | h;
            }
        }
    }
}

__global__ __launch_bounds__(256, 4) void spmm_k(const int* __restrict__ cnt,
                                                 const unsigned* __restrict__ bucket,
                                                 const unsigned* __restrict__ stateTh,
                                                 const float* __restrict__ inputsT,
                                                 const float* __restrict__ win_vals,
                                                 const float* __restrict__ win_bias,
                                                 const int* __restrict__ win_rows,
                                                 float* __restrict__ out) {
    const int slice = blockIdx.x & (NSLICE - 1);   // -> XCD parity (round-robin)
    const int tile  = blockIdx.x >> 1;
    const int c0 = tile * G;
    const int b0 = slice * 256;                    // this block's 256 b's
    const int lane = threadIdx.x & 63;
    const int w    = threadIdx.x >> 6;             // wave 0..3 owns cols 4w..4w+3

    __shared__ unsigned ebuf[G][LCAP];             // per-col packed entry lists
    __shared__ int   strue[G];                     // exact counts (staging)
    __shared__ int   spad[G];                      // counts padded to mult of 4
    __shared__ int   swr[G];
    __shared__ float sval[G], sbias[G];
    __shared__ float tbuf[G][260];                 // [col][b-local] reshuffle

    if (threadIdx.x < G) {
        const int c = c0 + threadIdx.x;
        int n = cnt[c];
        n = (n > LCAP) ? LCAP : n;
        strue[threadIdx.x] = n;
        spad[threadIdx.x]  = (n + 3) & ~3;
        swr[threadIdx.x]   = win_rows[c];
        sval[threadIdx.x]  = win_vals[c];
        sbias[threadIdx.x] = win_bias[c];
    }
    __syncthreads();

    // stage nnz lists, zero-padding the tail (zero entry: row 0, val 0 -> +0)
#pragma unroll
    for (int s = 0; s < G * LCAP; s += 256) {
        const int idx = s + threadIdx.x;
        const int g = idx >> 6, k = idx & (LCAP - 1);
        ebuf[g][k] = (k < strue[g]) ? bucket[(size_t)(c0 + g) * CAP + k] : 0u;
    }
    __syncthreads();

    const uint2* __restrict__ strow2 = (const uint2*)stateTh;  // row = 128 uint2
    const unsigned boff = (unsigned)(slice * 64) + lane;       // uint2 idx in row

    // each wave: 4 columns sequentially, exact (mult-4-padded) counts
#pragma unroll
    for (int g = 4 * w; g < 4 * w + 4; ++g) {
        const int n4 = spad[g];
        __half2 alo = int_as_h2(0u), ahi = alo;
        for (int k = 0; k < n4; k += 4) {
            const uint4 e = *(const uint4*)&ebuf[g][k];  // 4 entries, broadcast
            const uint2 p0 = strow2[((e.x >> 16) << 7) + boff];
            const uint2 p1 = strow2[((e.y >> 16) << 7) + boff];
            const uint2 p2 = strow2[((e.z >> 16) << 7) + boff];
            const uint2 p3 = strow2[((e.w >> 16) << 7) + boff];
            const __half2 v0 = duplo_h2(e.x), v1 = duplo_h2(e.y);
            const __half2 v2 = duplo_h2(e.z), v3 = duplo_h2(e.w);
            alo = __hfma2(int_as_h2(p0.x), v0, alo);
            ahi = __hfma2(int_as_h2(p0.y), v0, ahi);
            alo = __hfma2(int_as_h2(p1.x), v1, alo);
            ahi = __hfma2(int_as_h2(p1.y), v1, ahi);
            alo = __hfma2(int_as_h2(p2.x), v2, alo);
            ahi = __hfma2(int_as_h2(p2.y), v2, ahi);
            alo = __hfma2(int_as_h2(p3.x), v3, alo);
            ahi = __hfma2(int_as_h2(p3.y), v3, ahi);
        }

        // epilogue for column c0+g, this wave's 4 b's per lane
        const int c = c0 + g;
        const uint2 ps = strow2[((unsigned)c << 7) + boff];     // leak state
        const float s0 = __low2float(int_as_h2(ps.x)), s1 = __high2float(int_as_h2(ps.x));
        const float s2 = __low2float(int_as_h2(ps.y)), s3 = __high2float(int_as_h2(ps.y));
        const float4 inp = *(const float4*)(inputsT + (size_t)swr[g] * ESN_B + b0 + 4 * lane);
        const float vv = sval[g], bb = sbias[g];
        float4 o;
        o.x = s0 + ESN_ALPHA * (fast_tanh(inp.x * vv + bb + __low2float(alo))  - s0);
        o.y = s1 + ESN_ALPHA * (fast_tanh(inp.y * vv + bb + __high2float(alo)) - s1);
        o.z = s2 + ESN_ALPHA * (fast_tanh(inp.z * vv + bb + __low2float(ahi))  - s2);
        o.w = s3 + ESN_ALPHA * (fast_tanh(inp.w * vv + bb + __high2float(ahi)) - s3);
        *(float4*)(&tbuf[g][4 * lane]) = o;
    }
    __syncthreads();

    // reshuffle -> row-major out: 256 b-rows x 16 cols; lanes 0..3 cover one
    // 64 B run of a row -> coalesced float4 stores.
#pragma unroll
    for (int s = threadIdx.x; s < 4 * 256; s += 256) {
        const int jj = s & 3;            // which float4 within the 16 cols
        const int bl = s >> 2;           // b-local 0..255
        const float4 o4 = make_float4(tbuf[4 * jj + 0][bl], tbuf[4 * jj + 1][bl],
                                      tbuf[4 * jj + 2][bl], tbuf[4 * jj + 3][bl]);
        *(float4*)(out + (size_t)(b0 + bl) * ESN_N + c0 + 4 * jj) = o4;
    }
}

extern "C" void kernel_launch(void* const* d_in, const int* in_sizes, int n_in,
                              void* d_out, int out_size, void* d_ws, size_t ws_size,
                              hipStream_t stream) {
    const float* inputs    = (const float*)d_in[0];  // [B, D]
    const float* state     = (const float*)d_in[1];  // [B, N]
    const float* win_vals  = (const float*)d_in[2];  // [N]
    const float* win_bias  = (const float*)d_in[3];  // [N]
    const float* wres_vals = (const float*)d_in[4];  // [NNZ]
    const int*   win_rows  = (const int*)d_in[5];    // [N]
    const int*   wres_rows = (const int*)d_in[6];    // [NNZ]
    const int*   wres_cols = (const int*)d_in[7];    // [NNZ]
    float* out = (float*)d_out;                      // [B, N]

    const int NNZ = in_sizes[4];

    char* w = (char*)d_ws;
    unsigned* stateTh = (unsigned*)(w);                                  // 8 MB
    float*    inputsT = (float*)(w + (size_t)ESN_N * (ESN_B / 2) * 4);   // 512 KB
    unsigned* bucket  = (unsigned*)((char*)inputsT + (size_t)ESN_D * ESN_B * 4); // 4 MB
    int*      cnt     = (int*)((char*)bucket + (size_t)ESN_N * CAP * 4); // 32 KB

    hipMemsetAsync(cnt, 0, ESN_N * sizeof(int), stream);

    const int nb_sc = (NNZ + 255) / 256;
    const int nb = (ESN_N / 64) * (ESN_B / 64) + (ESN_D / 32) * (ESN_B / 32) + nb_sc;
    prep_k<<<nb, 256, 0, stream>>>(state, inputs, wres_rows, wres_cols, wres_vals,
                                   cnt, bucket, stateTh, inputsT, NNZ);

    spmm_k<<<(ESN_N / G) * NSLICE, 256, 0, stream>>>(cnt, bucket, stateTh, inputsT,
                                                     win_vals, win_bias, win_rows, out);
}